// Round 1
// 237.218 us; speedup vs baseline: 1.0349x; 1.0349x over previous
//
#include <hip/hip_runtime.h>
#include <hip/hip_bf16.h>

#define L_ 2048
#define D_ 192
#define HK_ 48
#define EPS_ 1e-3f
#define SCALE_ 0.28867513459481287f  // 1/sqrt(12)

typedef __hip_bfloat16 bf16;
typedef _Float16 f16;
typedef __fp16 hf16x2 __attribute__((ext_vector_type(2)));   // builtin return type
typedef _Float16 f16x4 __attribute__((ext_vector_type(4)));
typedef __bf16 bf16x8 __attribute__((ext_vector_type(8)));
typedef float  f32x4  __attribute__((ext_vector_type(4)));

__device__ __forceinline__ float b2f(bf16 x) { return __bfloat162float(x); }
__device__ __forceinline__ bf16 f2b(float x) { return __float2bfloat16(x); }

// ---------------------------------------------------------------------------
// K0: single prep kernel — all weight repacks in one launch (unchanged).
// ---------------------------------------------------------------------------
__global__ __launch_bounds__(256) void k_prep_all(
    const float* __restrict__ c1w, const float* __restrict__ c2w,
    const float* __restrict__ wq, const float* __restrict__ wk, const float* __restrict__ wv,
    const float* __restrict__ bq, const float* __restrict__ bk, const float* __restrict__ bv,
    const float* __restrict__ wo,
    bf16* __restrict__ wrep1, bf16* __restrict__ wrep2,
    bf16* __restrict__ wrepq, float* __restrict__ bias144, bf16* __restrict__ wrepo)
{
    const int i = blockIdx.x * 256 + threadIdx.x;
    if (i < 110592) {
        const int k = i / 192, n = i - k * 192;
        wrep1[((size_t)(k >> 5) * 192 + n) * 32 + (k & 31)] = f2b(c1w[i]);
    } else if (i < 221184) {
        const int j = i - 110592;
        const int k = j / 192, n = j - k * 192;
        wrep2[((size_t)(k >> 5) * 192 + n) * 32 + (k & 31)] = f2b(c2w[j]);
    } else if (i < 248832) {
        const int j = i - 221184;
        const int kb = j / 4608, rem = j % 4608;
        const int n = rem / 32, kk = rem % 32;
        const int k = kb * 32 + kk;
        float v;
        if (n < 48)       v = wq[k * HK_ + n] * SCALE_;
        else if (n < 96)  v = wk[k * HK_ + (n - 48)];
        else              v = wv[k * HK_ + (n - 96)];
        wrepq[j] = f2b(v);
    } else if (i < 248976) {
        const int j = i - 248832;
        bias144[j] = (j < 48) ? bq[j] * SCALE_
                   : (j < 96) ? bk[j - 48] : bv[j - 96];
    } else if (i < 261264) {
        const int j = i - 248976;
        const int kb = j / 6144, rem = j % 6144;
        const int n = rem / 32, kk = rem % 32;
        const int k = kb * 32 + kk;
        wrepo[j] = f2b(k < 48 ? wo[k * D_ + n] : 0.f);
    }
}

// ---------------------------------------------------------------------------
// K1: fused LN1 + QKV projection via MFMA (unchanged).
// ---------------------------------------------------------------------------
__global__ __launch_bounds__(256) void k_ln_qkv(
    const float* __restrict__ x, const float* __restrict__ g1, const float* __restrict__ b1,
    const bf16* __restrict__ wrep, const float* __restrict__ bias144,
    f16* __restrict__ qo, f16* __restrict__ ko, f16* __restrict__ vt)
{
    __shared__ bf16 xn[64 * 200];
    const int tid = threadIdx.x;
    const int wave = tid >> 6, lane = tid & 63;
    const int rowbase = blockIdx.x * 64;
    const int b = rowbase >> 11;
    const int lrow0 = rowbase & 2047;

    const float gg0 = g1[lane], gg1 = g1[lane + 64], gg2 = g1[lane + 128];
    const float bb0 = b1[lane], bb1 = b1[lane + 64], bb2 = b1[lane + 128];
    for (int i = 0; i < 16; ++i) {
        const int r = wave * 16 + i;
        const float* xp = x + (size_t)(rowbase + r) * D_;
        const float x0 = xp[lane];
        const float x1 = xp[lane + 64];
        const float x2 = xp[lane + 128];
        float s = x0 + x1 + x2;
        float q = x0 * x0 + x1 * x1 + x2 * x2;
        #pragma unroll
        for (int m = 1; m < 64; m <<= 1) {
            s += __shfl_xor(s, m, 64);
            q += __shfl_xor(q, m, 64);
        }
        const float mean = s * (1.0f / 192.0f);
        const float var  = q * (1.0f / 192.0f) - mean * mean;
        const float rs   = rsqrtf(var + EPS_);
        xn[r * 200 + lane]       = f2b((x0 - mean) * rs * gg0 + bb0);
        xn[r * 200 + lane + 64]  = f2b((x1 - mean) * rs * gg1 + bb1);
        xn[r * 200 + lane + 128] = f2b((x2 - mean) * rs * gg2 + bb2);
    }

    {
        const int h  = tid >> 6;
        const int vc = 12 + ((tid >> 4) & 3);
        const int p0 = lrow0 + (tid & 15) * 4;
        f16x4 vv;
        vv[0] = vv[1] = vv[2] = vv[3] = (vc == 12) ? (f16)1.0f : (f16)0.0f;
        *(f16x4*)(vt + ((size_t)(b * 4 + h) * 16 + vc) * 2048 + p0) = vv;
    }
    __syncthreads();

    const int l15 = lane & 15, q4 = lane >> 4;
    f32x4 acc[9];
    #pragma unroll
    for (int nt = 0; nt < 9; ++nt) acc[nt] = (f32x4){0.f, 0.f, 0.f, 0.f};

    const bf16* xrow = xn + (wave * 16 + l15) * 200 + q4 * 8;
    #pragma unroll
    for (int kb = 0; kb < 6; ++kb) {
        const bf16x8 a = *(const bf16x8*)(xrow + kb * 32);
        const bf16* wp = wrep + ((size_t)kb * 144 + l15) * 32 + q4 * 8;
        #pragma unroll
        for (int nt = 0; nt < 9; ++nt) {
            const bf16x8 bfr = *(const bf16x8*)(wp + (size_t)nt * 16 * 32);
            acc[nt] = __builtin_amdgcn_mfma_f32_16x16x32_bf16(a, bfr, acc[nt], 0, 0, 0);
        }
    }

    const int rw = rowbase + wave * 16 + q4 * 4;
    #pragma unroll
    for (int nt = 0; nt < 9; ++nt) {
        const int col = nt * 16 + l15;
        const float bd = bias144[col];
        if (nt < 3) {
            #pragma unroll
            for (int reg = 0; reg < 4; ++reg)
                qo[(size_t)(rw + reg) * HK_ + col] = (f16)(acc[nt][reg] + bd);
        } else if (nt < 6) {
            #pragma unroll
            for (int reg = 0; reg < 4; ++reg)
                ko[(size_t)(rw + reg) * HK_ + (col - 48)] = (f16)(acc[nt][reg] + bd);
        } else {
            const int vcol = col - 96;
            const int h = vcol / 12, c12 = vcol % 12;
            f16x4 vv;
            #pragma unroll
            for (int reg = 0; reg < 4; ++reg) vv[reg] = (f16)(acc[nt][reg] + bd);
            *(f16x4*)(vt + ((size_t)(b * 4 + h) * 16 + c12) * 2048 +
                      lrow0 + wave * 16 + q4 * 4) = vv;
        }
    }
}

// ---------------------------------------------------------------------------
// K2: MFMA attention partials (unchanged).
// ---------------------------------------------------------------------------
__global__ __launch_bounds__(256) void k_attn_part(
    const f16* __restrict__ qh, const f16* __restrict__ kh, const f16* __restrict__ vt,
    bf16* __restrict__ part_o, float* __restrict__ part_l)
{
    const int tid = threadIdx.x;
    const int wv = tid >> 6, lane = tid & 63;
    const int quad = lane >> 4, l15 = lane & 15;
    const int bh = blockIdx.x / 36;
    int r = blockIdx.x % 36;
    int qt = 0;
    while (r >= qt + 1) { r -= qt + 1; ++qt; }
    const int ks = r;
    const int b = bh >> 2, h = bh & 3;
    const size_t base  = (size_t)b * L_ * HK_ + h * 12;
    const size_t vbase = ((size_t)bh * 16 + l15) * 2048;
    const int kbase = ks * 256;
    const int qbase = qt * 256 + wv * 64;
    const bool diag = (ks == qt);
    const int ktmax = diag ? 4 * (wv + 1) : 16;

    f16x4 Qf[4];
    #pragma unroll
    for (int s = 0; s < 4; ++s) {
        f16x4 v;
        if (quad < 3)
            v = *(const f16x4*)(qh + base + (size_t)(qbase + s * 16 + l15) * HK_ + quad * 4);
        else { v[0] = (f16)1.0f; v[1] = 0; v[2] = 0; v[3] = 0; }   // hd12 = 1
        Qf[s] = v;
    }

    f32x4 O[4];
    #pragma unroll
    for (int s = 0; s < 4; ++s) O[s] = (f32x4){0.f, 0.f, 0.f, 0.f};

    for (int g = 0; g < ktmax; g += 4) {
        f16x4 Kg[4], Vg[4];
        #pragma unroll
        for (int u = 0; u < 4; ++u) {
            const int kt = g + u;
            f16x4 kf;
            if (quad < 3)
                kf = *(const f16x4*)(kh + base + (size_t)(kbase + kt * 16 + l15) * HK_ + quad * 4);
            else { kf[0] = (f16)-6.0f; kf[1] = 0; kf[2] = 0; kf[3] = 0; } // hd12 = -6
            Kg[u] = kf;
            Vg[u] = *(const f16x4*)(vt + vbase + kbase + kt * 16 + quad * 4);
        }
        #pragma unroll
        for (int u = 0; u < 4; ++u) {
            const int k0 = kbase + (g + u) * 16 + quad * 4;
            #pragma unroll
            for (int s = 0; s < 4; ++s) {
                f32x4 sc = (f32x4){0.f, 0.f, 0.f, 0.f};
                sc = __builtin_amdgcn_mfma_f32_16x16x16f16(Kg[u], Qf[s], sc, 0, 0, 0);
                float p0 = __expf(sc[0]), p1 = __expf(sc[1]);
                float p2 = __expf(sc[2]), p3 = __expf(sc[3]);
                if (diag) {
                    const int qg = qbase + s * 16 + l15;
                    p0 = (k0 + 0 <= qg) ? p0 : 0.f;
                    p1 = (k0 + 1 <= qg) ? p1 : 0.f;
                    p2 = (k0 + 2 <= qg) ? p2 : 0.f;
                    p3 = (k0 + 3 <= qg) ? p3 : 0.f;
                }
                const hf16x2 lo = __builtin_amdgcn_cvt_pkrtz(p0, p1);
                const hf16x2 hi = __builtin_amdgcn_cvt_pkrtz(p2, p3);
                f16x4 p;
                p[0] = (f16)lo[0]; p[1] = (f16)lo[1];
                p[2] = (f16)hi[0]; p[3] = (f16)hi[1];
                O[s] = __builtin_amdgcn_mfma_f32_16x16x16f16(p, Vg[u], O[s], 0, 0, 0);
            }
        }
    }

    const size_t pobase = (size_t)(bh * 8 + ks) * 2048;
    #pragma unroll
    for (int s = 0; s < 4; ++s) {
        const int q16 = qbase + s * 16;
        #pragma unroll
        for (int j = 0; j < 4; ++j) {
            const int qq = q16 + quad * 4 + j;
            if (l15 < 12)       part_o[(pobase + qq) * 12 + l15] = f2b(O[s][j]);
            else if (l15 == 12) part_l[pobase + qq] = O[s][j];
        }
    }
}

// ---------------------------------------------------------------------------
// K3: fused combine + out-proj (MFMA) + residual + LN2 (unchanged).
// ---------------------------------------------------------------------------
__global__ __launch_bounds__(256) void k_proj_ln2(
    const float* __restrict__ x, const bf16* __restrict__ part_o,
    const float* __restrict__ part_l, const bf16* __restrict__ wrepo,
    const float* __restrict__ bo, const float* __restrict__ g2,
    const float* __restrict__ lb2, bf16* __restrict__ x2b,
    bf16* __restrict__ xn2b)
{
    __shared__ bf16 ct[64 * 72];
    const int tid = threadIdx.x;
    const int wave = tid >> 6, lane = tid & 63;
    const int rowbase = blockIdx.x * 64;
    const int b = rowbase >> 11, lrow = rowbase & 2047;
    const int ns = (lrow >> 8) + 1;

    {
        const int rr = tid >> 2, h = tid & 3;
        const int q = lrow + rr;
        const bf16* op = part_o + ((size_t)(b * 4 + h) * 8 * 2048 + q) * 12;
        const float* lp = part_l + (size_t)(b * 4 + h) * 8 * 2048 + q;
        float o[12];
        #pragma unroll
        for (int i = 0; i < 12; ++i) o[i] = 0.f;
        float l = 0.f;
        for (int s = 0; s < ns; ++s) {
            l += lp[(size_t)s * 2048];
            #pragma unroll
            for (int i = 0; i < 12; ++i) o[i] += b2f(op[(size_t)s * 2048 * 12 + i]);
        }
        const float inv = 1.0f / l;
        #pragma unroll
        for (int i = 0; i < 12; ++i) ct[rr * 72 + h * 12 + i] = f2b(o[i] * inv);
        const int c0 = 48 + h * 4;
        #pragma unroll
        for (int i = 0; i < 4; ++i) ct[rr * 72 + c0 + i] = f2b(0.f);
    }
    __syncthreads();

    const int l15 = lane & 15, q4 = lane >> 4;
    f32x4 acc[12];
    #pragma unroll
    for (int nt = 0; nt < 12; ++nt) acc[nt] = (f32x4){0.f, 0.f, 0.f, 0.f};
    const bf16* arow = ct + (wave * 16 + l15) * 72 + q4 * 8;
    #pragma unroll
    for (int kb = 0; kb < 2; ++kb) {
        const bf16x8 a = *(const bf16x8*)(arow + kb * 32);
        const bf16* wp = wrepo + ((size_t)kb * 192 + l15) * 32 + q4 * 8;
        #pragma unroll
        for (int nt = 0; nt < 12; ++nt) {
            const bf16x8 bb = *(const bf16x8*)(wp + (size_t)nt * 16 * 32);
            acc[nt] = __builtin_amdgcn_mfma_f32_16x16x32_bf16(a, bb, acc[nt], 0, 0, 0);
        }
    }

    const int rw0 = rowbase + wave * 16 + q4 * 4;
    float sum[4] = {0.f, 0.f, 0.f, 0.f}, ssum[4] = {0.f, 0.f, 0.f, 0.f};
    #pragma unroll
    for (int nt = 0; nt < 12; ++nt) {
        const int col = nt * 16 + l15;
        const float bod = bo[col];
        #pragma unroll
        for (int reg = 0; reg < 4; ++reg) {
            const float v = acc[nt][reg] + bod + x[(size_t)(rw0 + reg) * D_ + col];
            acc[nt][reg] = v;
            x2b[(size_t)(rw0 + reg) * D_ + col] = f2b(v);
            sum[reg] += v; ssum[reg] += v * v;
        }
    }
    #pragma unroll
    for (int m = 1; m <= 8; m <<= 1) {
        #pragma unroll
        for (int reg = 0; reg < 4; ++reg) {
            sum[reg]  += __shfl_xor(sum[reg], m, 64);
            ssum[reg] += __shfl_xor(ssum[reg], m, 64);
        }
    }
    float mean[4], rs[4];
    #pragma unroll
    for (int reg = 0; reg < 4; ++reg) {
        mean[reg] = sum[reg] * (1.0f / 192.0f);
        const float var = ssum[reg] * (1.0f / 192.0f) - mean[reg] * mean[reg];
        rs[reg] = rsqrtf(var + EPS_);
    }
    #pragma unroll
    for (int nt = 0; nt < 12; ++nt) {
        const int col = nt * 16 + l15;
        const float g = g2[col], bb2 = lb2[col];
        #pragma unroll
        for (int reg = 0; reg < 4; ++reg)
            xn2b[(size_t)(rw0 + reg) * D_ + col] =
                f2b((acc[nt][reg] - mean[reg]) * rs[reg] * g + bb2);
    }
}

// ---------------------------------------------------------------------------
// K4/K5: conv as MFMA GEMM. Round 10 change: kernel was latency-bound
// (MfmaUtil 5%, HBM 13%, occupancy grid-limited at 2 waves/SIMD, VGPR=60 —
// compiler serialized the 126 loads/wave at ~870 cyc each = the whole 46 µs).
// Fix: __launch_bounds__(256,2) tells the allocator the true occupancy target
// (up to 256 VGPRs, still 8 waves/CU), and an explicit distance-2 ring
// prefetch (ab[3][4]/bb[3][3], fully unrolled so all ring indices are
// compile-time constants) keeps ~14 loads in flight while 12 MFMAs execute.
// ---------------------------------------------------------------------------
template <int IS_CONV1>
__global__ __launch_bounds__(256, 2) void k_conv_mfma(
    const bf16* __restrict__ act, const bf16* __restrict__ wrep,
    const float* __restrict__ bias, const bf16* __restrict__ x2b,
    bf16* __restrict__ outb, float* __restrict__ outf)
{
    const int wave = threadIdx.x >> 6, lane = threadIdx.x & 63;
    const int m16 = lane & 15, q = lane >> 4;
    const int rowbase = blockIdx.x * 64;

    f32x4 acc[4][3];
    #pragma unroll
    for (int mt = 0; mt < 4; ++mt)
        #pragma unroll
        for (int j = 0; j < 3; ++j) acc[mt][j] = (f32x4){0.f, 0.f, 0.f, 0.f};

    // ring prefetch buffers (all indices compile-time constant under unroll)
    bf16x8 ab[3][4];
    bf16x8 bb[3][3];

    #define LOADA(kb, mt) \
        (*(const bf16x8*)(act + ((long long)rowbase + (mt) * 16 + m16 + ((kb) / 6) - 1) * D_ \
                          + ((kb) % 6) * 32 + q * 8))
    #define LOADB(kb, j) \
        (*(const bf16x8*)(wrep + ((size_t)(kb) * 192 + m16) * 32 + q * 8 \
                          + (size_t)(wave * 3 + (j)) * 16 * 32))

    // prologue: fill ring slots 0 and 1
    #pragma unroll
    for (int p = 0; p < 2; ++p) {
        #pragma unroll
        for (int mt = 0; mt < 4; ++mt) ab[p][mt] = LOADA(p, mt);
        #pragma unroll
        for (int j = 0; j < 3; ++j)    bb[p][j]  = LOADB(p, j);
    }

    #pragma unroll
    for (int kb = 0; kb < 18; ++kb) {
        const int cur = kb % 3;
        if (kb + 2 < 18) {
            const int nxt = (kb + 2) % 3;
            #pragma unroll
            for (int mt = 0; mt < 4; ++mt) ab[nxt][mt] = LOADA(kb + 2, mt);
            #pragma unroll
            for (int j = 0; j < 3; ++j)    bb[nxt][j]  = LOADB(kb + 2, j);
        }
        #pragma unroll
        for (int j = 0; j < 3; ++j)
            #pragma unroll
            for (int mt = 0; mt < 4; ++mt)
                acc[mt][j] = __builtin_amdgcn_mfma_f32_16x16x32_bf16(
                    ab[cur][mt], bb[cur][j], acc[mt][j], 0, 0, 0);
    }
    #undef LOADA
    #undef LOADB

    #pragma unroll
    for (int j = 0; j < 3; ++j) {
        const int col = (wave * 3 + j) * 16 + m16;
        const float bd = bias[col];
        #pragma unroll
        for (int mt = 0; mt < 4; ++mt) {
            #pragma unroll
            for (int reg = 0; reg < 4; ++reg) {
                const int r = rowbase + mt * 16 + q * 4 + reg;
                const int m = r & (L_ - 1);
                const size_t idx = (size_t)r * D_ + col;
                if (IS_CONV1) {
                    float v = fmaxf(acc[mt][j][reg] + bd, 0.f);
                    if (m == 0 || m == L_ - 1) v = 0.f;
                    outb[idx] = f2b(v);
                } else {
                    float v = b2f(x2b[idx]);
                    if (m != 0 && m != L_ - 1) v += acc[mt][j][reg] + bd;
                    outf[idx] = v;
                }
            }
        }
    }
}

// ---------------------------------------------------------------------------
extern "C" void kernel_launch(void* const* d_in, const int* in_sizes, int n_in,
                              void* d_out, int out_size, void* d_ws, size_t ws_size,
                              hipStream_t stream)
{
    const float* x    = (const float*)d_in[0];
    const float* ln1g = (const float*)d_in[1];
    const float* ln1b = (const float*)d_in[2];
    const float* wq   = (const float*)d_in[3];
    const float* bq   = (const float*)d_in[4];
    const float* wk   = (const float*)d_in[5];
    const float* bk   = (const float*)d_in[6];
    const float* wv   = (const float*)d_in[7];
    const float* bv   = (const float*)d_in[8];
    const float* wo   = (const float*)d_in[9];
    const float* bo   = (const float*)d_in[10];
    const float* ln2g = (const float*)d_in[11];
    const float* ln2b = (const float*)d_in[12];
    const float* c1w  = (const float*)d_in[13];
    const float* c1b  = (const float*)d_in[14];
    const float* c2w  = (const float*)d_in[15];
    const float* c2b  = (const float*)d_in[16];

    const size_t ROWS = (size_t)16 * L_;            // 32768
    char* ws = (char*)d_ws;
    size_t off = 4096;                               // guard (conv row -1)
    bf16* xn2b = (bf16*)(ws + off); off += ROWS * D_ * 2;    // 12.6 MB
    off += 4096;                                     // guard
    bf16* hpb  = (bf16*)(ws + off); off += ROWS * D_ * 2;    // 12.6 MB
    off += 4096;                                     // guard
    bf16* x2b  = (bf16*)(ws + off); off += ROWS * D_ * 2;    // 12.6 MB
    f16* qb    = (f16*)(ws + off);   off += ROWS * HK_ * 2;  // 3.15 MB
    f16* kb    = (f16*)(ws + off);   off += ROWS * HK_ * 2;
    f16* vt    = (f16*)(ws + off);   off += (size_t)64 * 16 * 2048 * 2;   // 4.19 MB
    bf16* part_o = (bf16*)(ws + off); off += (size_t)64 * 8 * 2048 * 12 * 2; // 25.2 MB
    float* part_l = (float*)(ws + off); off += (size_t)64 * 8 * 2048 * 4;    //  4.2 MB
    bf16* wrep1 = (bf16*)(ws + off); off += 576 * 192 * 2;   // 221 KB
    bf16* wrep2 = (bf16*)(ws + off); off += 576 * 192 * 2;
    bf16* wrepq = (bf16*)(ws + off); off += 6 * 144 * 32 * 2;
    float* bias144 = (float*)(ws + off); off += 144 * 4;
    bf16* wrepo = (bf16*)(ws + off); off += 2 * 192 * 32 * 2; // total ~83 MB

    k_prep_all     <<<1021, 256, 0, stream>>>(c1w, c2w, wq, wk, wv, bq, bk, bv, wo,
                                              wrep1, wrep2, wrepq, bias144, wrepo);
    k_ln_qkv       <<< 512, 256, 0, stream>>>(x, ln1g, ln1b, wrepq, bias144, qb, kb, vt);
    k_attn_part    <<<64 * 36, 256, 0, stream>>>(qb, kb, vt, part_o, part_l);
    k_proj_ln2     <<< 512, 256, 0, stream>>>(x, part_o, part_l, wrepo, bo, ln2g, ln2b,
                                              x2b, xn2b);
    k_conv_mfma<1> <<< 512, 256, 0, stream>>>(xn2b, wrep1, c1b, nullptr, hpb, nullptr);
    k_conv_mfma<0> <<< 512, 256, 0, stream>>>(hpb, wrep2, c2b, x2b, nullptr, (float*)d_out);
}

// Round 2
// 202.147 us; speedup vs baseline: 1.2145x; 1.1735x over previous
//
#include <hip/hip_runtime.h>
#include <hip/hip_bf16.h>

#define L_ 2048
#define D_ 192
#define HK_ 48
#define EPS_ 1e-3f
#define SCALE_ 0.28867513459481287f  // 1/sqrt(12)

typedef __hip_bfloat16 bf16;
typedef _Float16 f16;
typedef __fp16 hf16x2 __attribute__((ext_vector_type(2)));   // builtin return type
typedef _Float16 f16x4 __attribute__((ext_vector_type(4)));
typedef __bf16 bf16x8 __attribute__((ext_vector_type(8)));
typedef float  f32x4  __attribute__((ext_vector_type(4)));

__device__ __forceinline__ float b2f(bf16 x) { return __bfloat162float(x); }
__device__ __forceinline__ bf16 f2b(float x) { return __float2bfloat16(x); }

// ---------------------------------------------------------------------------
// K0: single prep kernel — all weight repacks in one launch (unchanged).
// ---------------------------------------------------------------------------
__global__ __launch_bounds__(256) void k_prep_all(
    const float* __restrict__ c1w, const float* __restrict__ c2w,
    const float* __restrict__ wq, const float* __restrict__ wk, const float* __restrict__ wv,
    const float* __restrict__ bq, const float* __restrict__ bk, const float* __restrict__ bv,
    const float* __restrict__ wo,
    bf16* __restrict__ wrep1, bf16* __restrict__ wrep2,
    bf16* __restrict__ wrepq, float* __restrict__ bias144, bf16* __restrict__ wrepo)
{
    const int i = blockIdx.x * 256 + threadIdx.x;
    if (i < 110592) {
        const int k = i / 192, n = i - k * 192;
        wrep1[((size_t)(k >> 5) * 192 + n) * 32 + (k & 31)] = f2b(c1w[i]);
    } else if (i < 221184) {
        const int j = i - 110592;
        const int k = j / 192, n = j - k * 192;
        wrep2[((size_t)(k >> 5) * 192 + n) * 32 + (k & 31)] = f2b(c2w[j]);
    } else if (i < 248832) {
        const int j = i - 221184;
        const int kb = j / 4608, rem = j % 4608;
        const int n = rem / 32, kk = rem % 32;
        const int k = kb * 32 + kk;
        float v;
        if (n < 48)       v = wq[k * HK_ + n] * SCALE_;
        else if (n < 96)  v = wk[k * HK_ + (n - 48)];
        else              v = wv[k * HK_ + (n - 96)];
        wrepq[j] = f2b(v);
    } else if (i < 248976) {
        const int j = i - 248832;
        bias144[j] = (j < 48) ? bq[j] * SCALE_
                   : (j < 96) ? bk[j - 48] : bv[j - 96];
    } else if (i < 261264) {
        const int j = i - 248976;
        const int kb = j / 6144, rem = j % 6144;
        const int n = rem / 32, kk = rem % 32;
        const int k = kb * 32 + kk;
        wrepo[j] = f2b(k < 48 ? wo[k * D_ + n] : 0.f);
    }
}

// ---------------------------------------------------------------------------
// K1: fused LN1 + QKV projection via MFMA (unchanged).
// ---------------------------------------------------------------------------
__global__ __launch_bounds__(256) void k_ln_qkv(
    const float* __restrict__ x, const float* __restrict__ g1, const float* __restrict__ b1,
    const bf16* __restrict__ wrep, const float* __restrict__ bias144,
    f16* __restrict__ qo, f16* __restrict__ ko, f16* __restrict__ vt)
{
    __shared__ bf16 xn[64 * 200];
    const int tid = threadIdx.x;
    const int wave = tid >> 6, lane = tid & 63;
    const int rowbase = blockIdx.x * 64;
    const int b = rowbase >> 11;
    const int lrow0 = rowbase & 2047;

    const float gg0 = g1[lane], gg1 = g1[lane + 64], gg2 = g1[lane + 128];
    const float bb0 = b1[lane], bb1 = b1[lane + 64], bb2 = b1[lane + 128];
    for (int i = 0; i < 16; ++i) {
        const int r = wave * 16 + i;
        const float* xp = x + (size_t)(rowbase + r) * D_;
        const float x0 = xp[lane];
        const float x1 = xp[lane + 64];
        const float x2 = xp[lane + 128];
        float s = x0 + x1 + x2;
        float q = x0 * x0 + x1 * x1 + x2 * x2;
        #pragma unroll
        for (int m = 1; m < 64; m <<= 1) {
            s += __shfl_xor(s, m, 64);
            q += __shfl_xor(q, m, 64);
        }
        const float mean = s * (1.0f / 192.0f);
        const float var  = q * (1.0f / 192.0f) - mean * mean;
        const float rs   = rsqrtf(var + EPS_);
        xn[r * 200 + lane]       = f2b((x0 - mean) * rs * gg0 + bb0);
        xn[r * 200 + lane + 64]  = f2b((x1 - mean) * rs * gg1 + bb1);
        xn[r * 200 + lane + 128] = f2b((x2 - mean) * rs * gg2 + bb2);
    }

    {
        const int h  = tid >> 6;
        const int vc = 12 + ((tid >> 4) & 3);
        const int p0 = lrow0 + (tid & 15) * 4;
        f16x4 vv;
        vv[0] = vv[1] = vv[2] = vv[3] = (vc == 12) ? (f16)1.0f : (f16)0.0f;
        *(f16x4*)(vt + ((size_t)(b * 4 + h) * 16 + vc) * 2048 + p0) = vv;
    }
    __syncthreads();

    const int l15 = lane & 15, q4 = lane >> 4;
    f32x4 acc[9];
    #pragma unroll
    for (int nt = 0; nt < 9; ++nt) acc[nt] = (f32x4){0.f, 0.f, 0.f, 0.f};

    const bf16* xrow = xn + (wave * 16 + l15) * 200 + q4 * 8;
    #pragma unroll
    for (int kb = 0; kb < 6; ++kb) {
        const bf16x8 a = *(const bf16x8*)(xrow + kb * 32);
        const bf16* wp = wrep + ((size_t)kb * 144 + l15) * 32 + q4 * 8;
        #pragma unroll
        for (int nt = 0; nt < 9; ++nt) {
            const bf16x8 bfr = *(const bf16x8*)(wp + (size_t)nt * 16 * 32);
            acc[nt] = __builtin_amdgcn_mfma_f32_16x16x32_bf16(a, bfr, acc[nt], 0, 0, 0);
        }
    }

    const int rw = rowbase + wave * 16 + q4 * 4;
    #pragma unroll
    for (int nt = 0; nt < 9; ++nt) {
        const int col = nt * 16 + l15;
        const float bd = bias144[col];
        if (nt < 3) {
            #pragma unroll
            for (int reg = 0; reg < 4; ++reg)
                qo[(size_t)(rw + reg) * HK_ + col] = (f16)(acc[nt][reg] + bd);
        } else if (nt < 6) {
            #pragma unroll
            for (int reg = 0; reg < 4; ++reg)
                ko[(size_t)(rw + reg) * HK_ + (col - 48)] = (f16)(acc[nt][reg] + bd);
        } else {
            const int vcol = col - 96;
            const int h = vcol / 12, c12 = vcol % 12;
            f16x4 vv;
            #pragma unroll
            for (int reg = 0; reg < 4; ++reg) vv[reg] = (f16)(acc[nt][reg] + bd);
            *(f16x4*)(vt + ((size_t)(b * 4 + h) * 16 + c12) * 2048 +
                      lrow0 + wave * 16 + q4 * 4) = vv;
        }
    }
}

// ---------------------------------------------------------------------------
// K2: MFMA attention partials (unchanged).
// ---------------------------------------------------------------------------
__global__ __launch_bounds__(256) void k_attn_part(
    const f16* __restrict__ qh, const f16* __restrict__ kh, const f16* __restrict__ vt,
    bf16* __restrict__ part_o, float* __restrict__ part_l)
{
    const int tid = threadIdx.x;
    const int wv = tid >> 6, lane = tid & 63;
    const int quad = lane >> 4, l15 = lane & 15;
    const int bh = blockIdx.x / 36;
    int r = blockIdx.x % 36;
    int qt = 0;
    while (r >= qt + 1) { r -= qt + 1; ++qt; }
    const int ks = r;
    const int b = bh >> 2, h = bh & 3;
    const size_t base  = (size_t)b * L_ * HK_ + h * 12;
    const size_t vbase = ((size_t)bh * 16 + l15) * 2048;
    const int kbase = ks * 256;
    const int qbase = qt * 256 + wv * 64;
    const bool diag = (ks == qt);
    const int ktmax = diag ? 4 * (wv + 1) : 16;

    f16x4 Qf[4];
    #pragma unroll
    for (int s = 0; s < 4; ++s) {
        f16x4 v;
        if (quad < 3)
            v = *(const f16x4*)(qh + base + (size_t)(qbase + s * 16 + l15) * HK_ + quad * 4);
        else { v[0] = (f16)1.0f; v[1] = 0; v[2] = 0; v[3] = 0; }   // hd12 = 1
        Qf[s] = v;
    }

    f32x4 O[4];
    #pragma unroll
    for (int s = 0; s < 4; ++s) O[s] = (f32x4){0.f, 0.f, 0.f, 0.f};

    for (int g = 0; g < ktmax; g += 4) {
        f16x4 Kg[4], Vg[4];
        #pragma unroll
        for (int u = 0; u < 4; ++u) {
            const int kt = g + u;
            f16x4 kf;
            if (quad < 3)
                kf = *(const f16x4*)(kh + base + (size_t)(kbase + kt * 16 + l15) * HK_ + quad * 4);
            else { kf[0] = (f16)-6.0f; kf[1] = 0; kf[2] = 0; kf[3] = 0; } // hd12 = -6
            Kg[u] = kf;
            Vg[u] = *(const f16x4*)(vt + vbase + kbase + kt * 16 + quad * 4);
        }
        #pragma unroll
        for (int u = 0; u < 4; ++u) {
            const int k0 = kbase + (g + u) * 16 + quad * 4;
            #pragma unroll
            for (int s = 0; s < 4; ++s) {
                f32x4 sc = (f32x4){0.f, 0.f, 0.f, 0.f};
                sc = __builtin_amdgcn_mfma_f32_16x16x16f16(Kg[u], Qf[s], sc, 0, 0, 0);
                float p0 = __expf(sc[0]), p1 = __expf(sc[1]);
                float p2 = __expf(sc[2]), p3 = __expf(sc[3]);
                if (diag) {
                    const int qg = qbase + s * 16 + l15;
                    p0 = (k0 + 0 <= qg) ? p0 : 0.f;
                    p1 = (k0 + 1 <= qg) ? p1 : 0.f;
                    p2 = (k0 + 2 <= qg) ? p2 : 0.f;
                    p3 = (k0 + 3 <= qg) ? p3 : 0.f;
                }
                const hf16x2 lo = __builtin_amdgcn_cvt_pkrtz(p0, p1);
                const hf16x2 hi = __builtin_amdgcn_cvt_pkrtz(p2, p3);
                f16x4 p;
                p[0] = (f16)lo[0]; p[1] = (f16)lo[1];
                p[2] = (f16)hi[0]; p[3] = (f16)hi[1];
                O[s] = __builtin_amdgcn_mfma_f32_16x16x16f16(p, Vg[u], O[s], 0, 0, 0);
            }
        }
    }

    const size_t pobase = (size_t)(bh * 8 + ks) * 2048;
    #pragma unroll
    for (int s = 0; s < 4; ++s) {
        const int q16 = qbase + s * 16;
        #pragma unroll
        for (int j = 0; j < 4; ++j) {
            const int qq = q16 + quad * 4 + j;
            if (l15 < 12)       part_o[(pobase + qq) * 12 + l15] = f2b(O[s][j]);
            else if (l15 == 12) part_l[pobase + qq] = O[s][j];
        }
    }
}

// ---------------------------------------------------------------------------
// K3: fused combine + out-proj (MFMA) + residual + LN2 (unchanged).
// ---------------------------------------------------------------------------
__global__ __launch_bounds__(256) void k_proj_ln2(
    const float* __restrict__ x, const bf16* __restrict__ part_o,
    const float* __restrict__ part_l, const bf16* __restrict__ wrepo,
    const float* __restrict__ bo, const float* __restrict__ g2,
    const float* __restrict__ lb2, bf16* __restrict__ x2b,
    bf16* __restrict__ xn2b)
{
    __shared__ bf16 ct[64 * 72];
    const int tid = threadIdx.x;
    const int wave = tid >> 6, lane = tid & 63;
    const int rowbase = blockIdx.x * 64;
    const int b = rowbase >> 11, lrow = rowbase & 2047;
    const int ns = (lrow >> 8) + 1;

    {
        const int rr = tid >> 2, h = tid & 3;
        const int q = lrow + rr;
        const bf16* op = part_o + ((size_t)(b * 4 + h) * 8 * 2048 + q) * 12;
        const float* lp = part_l + (size_t)(b * 4 + h) * 8 * 2048 + q;
        float o[12];
        #pragma unroll
        for (int i = 0; i < 12; ++i) o[i] = 0.f;
        float l = 0.f;
        for (int s = 0; s < ns; ++s) {
            l += lp[(size_t)s * 2048];
            #pragma unroll
            for (int i = 0; i < 12; ++i) o[i] += b2f(op[(size_t)s * 2048 * 12 + i]);
        }
        const float inv = 1.0f / l;
        #pragma unroll
        for (int i = 0; i < 12; ++i) ct[rr * 72 + h * 12 + i] = f2b(o[i] * inv);
        const int c0 = 48 + h * 4;
        #pragma unroll
        for (int i = 0; i < 4; ++i) ct[rr * 72 + c0 + i] = f2b(0.f);
    }
    __syncthreads();

    const int l15 = lane & 15, q4 = lane >> 4;
    f32x4 acc[12];
    #pragma unroll
    for (int nt = 0; nt < 12; ++nt) acc[nt] = (f32x4){0.f, 0.f, 0.f, 0.f};
    const bf16* arow = ct + (wave * 16 + l15) * 72 + q4 * 8;
    #pragma unroll
    for (int kb = 0; kb < 2; ++kb) {
        const bf16x8 a = *(const bf16x8*)(arow + kb * 32);
        const bf16* wp = wrepo + ((size_t)kb * 192 + l15) * 32 + q4 * 8;
        #pragma unroll
        for (int nt = 0; nt < 12; ++nt) {
            const bf16x8 bb = *(const bf16x8*)(wp + (size_t)nt * 16 * 32);
            acc[nt] = __builtin_amdgcn_mfma_f32_16x16x32_bf16(a, bb, acc[nt], 0, 0, 0);
        }
    }

    const int rw0 = rowbase + wave * 16 + q4 * 4;
    float sum[4] = {0.f, 0.f, 0.f, 0.f}, ssum[4] = {0.f, 0.f, 0.f, 0.f};
    #pragma unroll
    for (int nt = 0; nt < 12; ++nt) {
        const int col = nt * 16 + l15;
        const float bod = bo[col];
        #pragma unroll
        for (int reg = 0; reg < 4; ++reg) {
            const float v = acc[nt][reg] + bod + x[(size_t)(rw0 + reg) * D_ + col];
            acc[nt][reg] = v;
            x2b[(size_t)(rw0 + reg) * D_ + col] = f2b(v);
            sum[reg] += v; ssum[reg] += v * v;
        }
    }
    #pragma unroll
    for (int m = 1; m <= 8; m <<= 1) {
        #pragma unroll
        for (int reg = 0; reg < 4; ++reg) {
            sum[reg]  += __shfl_xor(sum[reg], m, 64);
            ssum[reg] += __shfl_xor(ssum[reg], m, 64);
        }
    }
    float mean[4], rs[4];
    #pragma unroll
    for (int reg = 0; reg < 4; ++reg) {
        mean[reg] = sum[reg] * (1.0f / 192.0f);
        const float var = ssum[reg] * (1.0f / 192.0f) - mean[reg] * mean[reg];
        rs[reg] = rsqrtf(var + EPS_);
    }
    #pragma unroll
    for (int nt = 0; nt < 12; ++nt) {
        const int col = nt * 16 + l15;
        const float g = g2[col], bb2 = lb2[col];
        #pragma unroll
        for (int reg = 0; reg < 4; ++reg)
            xn2b[(size_t)(rw0 + reg) * D_ + col] =
                f2b((acc[nt][reg] - mean[reg]) * rs[reg] * g + bb2);
    }
}

// ---------------------------------------------------------------------------
// K4: FUSED conv1+conv2. Round-2 change. Theory: the old split kernels re-read
// the block's 26 KB activation panel ~12x from L2/L3 (each (kb,mt) step
// re-fetched it) and round-tripped 25 MB of h through global. Fix:
//  - stage xn2b rows [rowbase-2, rowbase+65] ONCE into LDS (400-byte row
//    stride: 100 dwords = 4 mod 32 banks -> the 16-row b128 fragment read is
//    spread uniformly over all 32 banks, conflict-free, no XOR needed),
//  - conv1 -> registers -> h-tile in LDS (never global), barrier,
//  - conv2 reads h from LDS, adds x2b residual (preloaded), writes f32 out.
// Boundary semantics identical to the old pair: h rows at m==0/m==L-1 are
// written as 0; out rows m==0/m==L-1 bypass the conv sum. Halo rows outside
// the batch produce garbage only in h rows that feed discarded outputs
// (MFMA D-row r depends only on A-row r).
// ---------------------------------------------------------------------------
#define INROWB 400            // LDS row stride in bytes (192*2=384 data + 16 pad)
#define HTOFF  27200          // 68 rows * 400 B
__global__ __launch_bounds__(256, 2) void k_conv_fused(
    const bf16* __restrict__ act, const bf16* __restrict__ w1,
    const float* __restrict__ b1c, const bf16* __restrict__ w2,
    const float* __restrict__ b2c, const bf16* __restrict__ x2b,
    float* __restrict__ outf)
{
    __shared__ __align__(16) char lds[27200 + 26400];   // in-tile 68 + h-tile 66 rows

    const int tid = threadIdx.x;
    const int wave = tid >> 6, lane = tid & 63;
    const int m16 = lane & 15, q = lane >> 4;
    const int rowbase = blockIdx.x * 64;
    const int lrow = rowbase & (L_ - 1);

    // ---- stage xn2b rows rowbase-2 .. rowbase+65 (68 rows x 384 B) ----
    {
        const bf16* src0 = act + ((long long)rowbase - 2) * D_;
        bf16x8 v[7];
        int dst[7];
        #pragma unroll
        for (int i = 0; i < 7; ++i) {
            const int g = tid + i * 256;
            if (g < 1632) {
                v[i] = *(const bf16x8*)(src0 + g * 8);
                const int row = (g * 2731) >> 16;          // g / 24
                dst[i] = row * INROWB + (g - row * 24) * 16;
            }
        }
        #pragma unroll
        for (int i = 0; i < 7; ++i) {
            const int g = tid + i * 256;
            if (g < 1632) *(bf16x8*)(lds + dst[i]) = v[i];
        }
    }

    const int laneA = m16 * INROWB + q * 16;  // per-lane A-fragment byte offset
    const int colw = wave * 48;
    float bd1[3], bd2[3];
    #pragma unroll
    for (int j = 0; j < 3; ++j) {
        bd1[j] = b1c[colw + j * 16 + m16];
        bd2[j] = b2c[colw + j * 16 + m16];
    }
    __syncthreads();

    // ---- conv1: 5 M-tiles (80 rows, 66 valid) x 3 N-tiles, K=576 ----
    f32x4 acc1[5][3];
    #pragma unroll
    for (int mt = 0; mt < 5; ++mt)
        #pragma unroll
        for (int j = 0; j < 3; ++j) acc1[mt][j] = (f32x4){0.f, 0.f, 0.f, 0.f};

    #define LOADB(w, kb, j) \
        (*(const bf16x8*)((w) + ((size_t)(kb) * 192 + m16) * 32 + q * 8 \
                          + (size_t)(wave * 3 + (j)) * 16 * 32))
    {
        bf16x8 bB[2][3];
        #pragma unroll
        for (int j = 0; j < 3; ++j) bB[0][j] = LOADB(w1, 0, j);
        #pragma unroll
        for (int kb = 0; kb < 18; ++kb) {
            if (kb + 1 < 18) {
                #pragma unroll
                for (int j = 0; j < 3; ++j) bB[(kb + 1) & 1][j] = LOADB(w1, kb + 1, j);
            }
            const int t = kb / 6, c6 = kb % 6;
            bf16x8 a[5];
            #pragma unroll
            for (int mt = 0; mt < 5; ++mt)
                a[mt] = *(const bf16x8*)(lds + laneA + (mt * 16 + t) * INROWB + c6 * 64);
            #pragma unroll
            for (int j = 0; j < 3; ++j)
                #pragma unroll
                for (int mt = 0; mt < 5; ++mt)
                    acc1[mt][j] = __builtin_amdgcn_mfma_f32_16x16x32_bf16(
                        a[mt], bB[kb & 1][j], acc1[mt][j], 0, 0, 0);
        }
    }

    // ---- h-tile (relu, edge-zero) -> LDS rows 0..65 ----
    #pragma unroll
    for (int mt = 0; mt < 5; ++mt)
        #pragma unroll
        for (int j = 0; j < 3; ++j)
            #pragma unroll
            for (int reg = 0; reg < 4; ++reg) {
                const int hr = mt * 16 + q * 4 + reg;
                if (hr < 66) {
                    const int hm = lrow + hr - 1;
                    float v = fmaxf(acc1[mt][j][reg] + bd1[j], 0.f);
                    if (hm == 0 || hm == L_ - 1) v = 0.f;
                    *(bf16*)(lds + HTOFF + hr * INROWB + (colw + j * 16 + m16) * 2) = f2b(v);
                }
            }
    __syncthreads();

    // ---- preload residual x2b (latency hidden under conv2 MFMAs) ----
    float xr[3][4][4];
    #pragma unroll
    for (int j = 0; j < 3; ++j)
        #pragma unroll
        for (int mt = 0; mt < 4; ++mt)
            #pragma unroll
            for (int reg = 0; reg < 4; ++reg)
                xr[j][mt][reg] = b2f(x2b[(size_t)(rowbase + mt * 16 + q * 4 + reg) * D_
                                         + colw + j * 16 + m16]);

    // ---- conv2: 4 M-tiles x 3 N-tiles, A from h-tile ----
    f32x4 acc2[4][3];
    #pragma unroll
    for (int mt = 0; mt < 4; ++mt)
        #pragma unroll
        for (int j = 0; j < 3; ++j) acc2[mt][j] = (f32x4){0.f, 0.f, 0.f, 0.f};
    {
        bf16x8 bB[2][3];
        #pragma unroll
        for (int j = 0; j < 3; ++j) bB[0][j] = LOADB(w2, 0, j);
        #pragma unroll
        for (int kb = 0; kb < 18; ++kb) {
            if (kb + 1 < 18) {
                #pragma unroll
                for (int j = 0; j < 3; ++j) bB[(kb + 1) & 1][j] = LOADB(w2, kb + 1, j);
            }
            const int t = kb / 6, c6 = kb % 6;
            bf16x8 a[4];
            #pragma unroll
            for (int mt = 0; mt < 4; ++mt)
                a[mt] = *(const bf16x8*)(lds + HTOFF + laneA + (mt * 16 + t) * INROWB + c6 * 64);
            #pragma unroll
            for (int j = 0; j < 3; ++j)
                #pragma unroll
                for (int mt = 0; mt < 4; ++mt)
                    acc2[mt][j] = __builtin_amdgcn_mfma_f32_16x16x32_bf16(
                        a[mt], bB[kb & 1][j], acc2[mt][j], 0, 0, 0);
        }
    }
    #undef LOADB

    // ---- epilogue: residual + store f32 ----
    #pragma unroll
    for (int j = 0; j < 3; ++j)
        #pragma unroll
        for (int mt = 0; mt < 4; ++mt)
            #pragma unroll
            for (int reg = 0; reg < 4; ++reg) {
                const int r = rowbase + mt * 16 + q * 4 + reg;
                const int m = r & (L_ - 1);
                float v = xr[j][mt][reg];
                if (m != 0 && m != L_ - 1) v += acc2[mt][j][reg] + bd2[j];
                outf[(size_t)r * D_ + colw + j * 16 + m16] = v;
            }
}

// ---------------------------------------------------------------------------
extern "C" void kernel_launch(void* const* d_in, const int* in_sizes, int n_in,
                              void* d_out, int out_size, void* d_ws, size_t ws_size,
                              hipStream_t stream)
{
    const float* x    = (const float*)d_in[0];
    const float* ln1g = (const float*)d_in[1];
    const float* ln1b = (const float*)d_in[2];
    const float* wq   = (const float*)d_in[3];
    const float* bq   = (const float*)d_in[4];
    const float* wk   = (const float*)d_in[5];
    const float* bk   = (const float*)d_in[6];
    const float* wv   = (const float*)d_in[7];
    const float* bv   = (const float*)d_in[8];
    const float* wo   = (const float*)d_in[9];
    const float* bo   = (const float*)d_in[10];
    const float* ln2g = (const float*)d_in[11];
    const float* ln2b = (const float*)d_in[12];
    const float* c1w  = (const float*)d_in[13];
    const float* c1b  = (const float*)d_in[14];
    const float* c2w  = (const float*)d_in[15];
    const float* c2b  = (const float*)d_in[16];

    const size_t ROWS = (size_t)16 * L_;            // 32768
    char* ws = (char*)d_ws;
    size_t off = 4096;                               // guard (conv halo row -2)
    bf16* xn2b = (bf16*)(ws + off); off += ROWS * D_ * 2;    // 12.6 MB
    off += 4096;                                     // guard (conv halo row +65)
    bf16* hpb  = (bf16*)(ws + off); off += ROWS * D_ * 2;    // (unused, keeps guard)
    off += 4096;                                     // guard
    bf16* x2b  = (bf16*)(ws + off); off += ROWS * D_ * 2;    // 12.6 MB
    f16* qb    = (f16*)(ws + off);   off += ROWS * HK_ * 2;  // 3.15 MB
    f16* kb    = (f16*)(ws + off);   off += ROWS * HK_ * 2;
    f16* vt    = (f16*)(ws + off);   off += (size_t)64 * 16 * 2048 * 2;   // 4.19 MB
    bf16* part_o = (bf16*)(ws + off); off += (size_t)64 * 8 * 2048 * 12 * 2; // 25.2 MB
    float* part_l = (float*)(ws + off); off += (size_t)64 * 8 * 2048 * 4;    //  4.2 MB
    bf16* wrep1 = (bf16*)(ws + off); off += 576 * 192 * 2;   // 221 KB
    bf16* wrep2 = (bf16*)(ws + off); off += 576 * 192 * 2;
    bf16* wrepq = (bf16*)(ws + off); off += 6 * 144 * 32 * 2;
    float* bias144 = (float*)(ws + off); off += 144 * 4;
    bf16* wrepo = (bf16*)(ws + off); off += 2 * 192 * 32 * 2; // total ~83 MB

    (void)hpb;
    k_prep_all   <<<1021, 256, 0, stream>>>(c1w, c2w, wq, wk, wv, bq, bk, bv, wo,
                                            wrep1, wrep2, wrepq, bias144, wrepo);
    k_ln_qkv     <<< 512, 256, 0, stream>>>(x, ln1g, ln1b, wrepq, bias144, qb, kb, vt);
    k_attn_part  <<<64 * 36, 256, 0, stream>>>(qb, kb, vt, part_o, part_l);
    k_proj_ln2   <<< 512, 256, 0, stream>>>(x, part_o, part_l, wrepo, bo, ln2g, ln2b,
                                            x2b, xn2b);
    k_conv_fused <<< 512, 256, 0, stream>>>(xn2b, wrep1, c1b, wrep2, c2b, x2b,
                                            (float*)d_out);
}

// Round 3
// 194.336 us; speedup vs baseline: 1.2633x; 1.0402x over previous
//
#include <hip/hip_runtime.h>
#include <hip/hip_bf16.h>

#define L_ 2048
#define D_ 192
#define HK_ 48
#define EPS_ 1e-3f
#define SCALE_ 0.28867513459481287f  // 1/sqrt(12)
#define LOG2E_ 1.4426950408889634f

typedef __hip_bfloat16 bf16;
typedef _Float16 f16;
typedef __fp16 hf16x2 __attribute__((ext_vector_type(2)));   // builtin return type
typedef _Float16 f16x4 __attribute__((ext_vector_type(4)));
typedef __bf16 bf16x8 __attribute__((ext_vector_type(8)));
typedef float  f32x4  __attribute__((ext_vector_type(4)));

__device__ __forceinline__ float b2f(bf16 x) { return __bfloat162float(x); }
__device__ __forceinline__ bf16 f2b(float x) { return __float2bfloat16(x); }

// ---------------------------------------------------------------------------
// K0: single prep kernel — all weight repacks in one launch.
// Round-3 change: Q-side weights/bias additionally scaled by log2(e) so the
// attention softmax uses a single v_exp_f32 (exp2) instead of mul+exp.
// ---------------------------------------------------------------------------
__global__ __launch_bounds__(256) void k_prep_all(
    const float* __restrict__ c1w, const float* __restrict__ c2w,
    const float* __restrict__ wq, const float* __restrict__ wk, const float* __restrict__ wv,
    const float* __restrict__ bq, const float* __restrict__ bk, const float* __restrict__ bv,
    const float* __restrict__ wo,
    bf16* __restrict__ wrep1, bf16* __restrict__ wrep2,
    bf16* __restrict__ wrepq, float* __restrict__ bias144, bf16* __restrict__ wrepo)
{
    const int i = blockIdx.x * 256 + threadIdx.x;
    if (i < 110592) {
        const int k = i / 192, n = i - k * 192;
        wrep1[((size_t)(k >> 5) * 192 + n) * 32 + (k & 31)] = f2b(c1w[i]);
    } else if (i < 221184) {
        const int j = i - 110592;
        const int k = j / 192, n = j - k * 192;
        wrep2[((size_t)(k >> 5) * 192 + n) * 32 + (k & 31)] = f2b(c2w[j]);
    } else if (i < 248832) {
        const int j = i - 221184;
        const int kb = j / 4608, rem = j % 4608;
        const int n = rem / 32, kk = rem % 32;
        const int k = kb * 32 + kk;
        float v;
        if (n < 48)       v = wq[k * HK_ + n] * (SCALE_ * LOG2E_);
        else if (n < 96)  v = wk[k * HK_ + (n - 48)];
        else              v = wv[k * HK_ + (n - 96)];
        wrepq[j] = f2b(v);
    } else if (i < 248976) {
        const int j = i - 248832;
        bias144[j] = (j < 48) ? bq[j] * (SCALE_ * LOG2E_)
                   : (j < 96) ? bk[j - 48] : bv[j - 96];
    } else if (i < 261264) {
        const int j = i - 248976;
        const int kb = j / 6144, rem = j % 6144;
        const int n = rem / 32, kk = rem % 32;
        const int k = kb * 32 + kk;
        wrepo[j] = f2b(k < 48 ? wo[k * D_ + n] : 0.f);
    }
}

// ---------------------------------------------------------------------------
// K1: fused LN1 + QKV projection via MFMA.
// Round-3 change: 32-row tiles, grid 1024 (was 512/64) -> 4 blocks/CU,
// 4 waves/SIMD (was 2). MFMA N-tiles split across wave pairs:
// wave = rt*2+g; g=0 -> nt 0..4, g=1 -> nt 5..8.
// ---------------------------------------------------------------------------
__global__ __launch_bounds__(256, 4) void k_ln_qkv(
    const float* __restrict__ x, const float* __restrict__ g1, const float* __restrict__ b1,
    const bf16* __restrict__ wrep, const float* __restrict__ bias144,
    f16* __restrict__ qo, f16* __restrict__ ko, f16* __restrict__ vt)
{
    __shared__ bf16 xn[32 * 200];
    const int tid = threadIdx.x;
    const int wave = tid >> 6, lane = tid & 63;
    const int rowbase = blockIdx.x * 32;
    const int b = rowbase >> 11;
    const int lrow0 = rowbase & 2047;

    const float gg0 = g1[lane], gg1 = g1[lane + 64], gg2 = g1[lane + 128];
    const float bb0 = b1[lane], bb1 = b1[lane + 64], bb2 = b1[lane + 128];
    for (int i = 0; i < 8; ++i) {
        const int r = wave * 8 + i;
        const float* xp = x + (size_t)(rowbase + r) * D_;
        const float x0 = xp[lane];
        const float x1 = xp[lane + 64];
        const float x2 = xp[lane + 128];
        float s = x0 + x1 + x2;
        float q = x0 * x0 + x1 * x1 + x2 * x2;
        #pragma unroll
        for (int m = 1; m < 64; m <<= 1) {
            s += __shfl_xor(s, m, 64);
            q += __shfl_xor(q, m, 64);
        }
        const float mean = s * (1.0f / 192.0f);
        const float var  = q * (1.0f / 192.0f) - mean * mean;
        const float rs   = rsqrtf(var + EPS_);
        xn[r * 200 + lane]       = f2b((x0 - mean) * rs * gg0 + bb0);
        xn[r * 200 + lane + 64]  = f2b((x1 - mean) * rs * gg1 + bb1);
        xn[r * 200 + lane + 128] = f2b((x2 - mean) * rs * gg2 + bb2);
    }

    if (tid < 128) {
        const int h  = tid >> 5;
        const int vc = 12 + ((tid >> 3) & 3);
        const int p0 = lrow0 + (tid & 7) * 4;
        f16x4 vv;
        vv[0] = vv[1] = vv[2] = vv[3] = (vc == 12) ? (f16)1.0f : (f16)0.0f;
        *(f16x4*)(vt + ((size_t)(b * 4 + h) * 16 + vc) * 2048 + p0) = vv;
    }
    __syncthreads();

    const int l15 = lane & 15, q4 = lane >> 4;
    const int rt = wave >> 1, g = wave & 1;
    const int ntlim = 5 - g;                 // g=0: nt 0..4, g=1: nt 0..3 (+5)
    f32x4 acc[5];
    #pragma unroll
    for (int nt = 0; nt < 5; ++nt) acc[nt] = (f32x4){0.f, 0.f, 0.f, 0.f};

    const bf16* xrow = xn + (rt * 16 + l15) * 200 + q4 * 8;
    #pragma unroll
    for (int kb = 0; kb < 6; ++kb) {
        const bf16x8 a = *(const bf16x8*)(xrow + kb * 32);
        const bf16* wp = wrep + ((size_t)kb * 144 + l15) * 32 + q4 * 8
                       + (size_t)(g * 5) * 16 * 32;
        #pragma unroll
        for (int nt = 0; nt < 5; ++nt) {
            if (nt < ntlim) {
                const bf16x8 bfr = *(const bf16x8*)(wp + (size_t)nt * 16 * 32);
                acc[nt] = __builtin_amdgcn_mfma_f32_16x16x32_bf16(a, bfr, acc[nt], 0, 0, 0);
            }
        }
    }

    const int rw = rowbase + rt * 16 + q4 * 4;
    #pragma unroll
    for (int nt = 0; nt < 5; ++nt) {
        if (nt < ntlim) {
            const int ntg = g * 5 + nt;
            const int col = ntg * 16 + l15;
            const float bd = bias144[col];
            if (ntg < 3) {
                #pragma unroll
                for (int reg = 0; reg < 4; ++reg)
                    qo[(size_t)(rw + reg) * HK_ + col] = (f16)(acc[nt][reg] + bd);
            } else if (ntg < 6) {
                #pragma unroll
                for (int reg = 0; reg < 4; ++reg)
                    ko[(size_t)(rw + reg) * HK_ + (col - 48)] = (f16)(acc[nt][reg] + bd);
            } else {
                const int vcol = col - 96;
                const int h = vcol / 12, c12 = vcol % 12;
                f16x4 vv;
                #pragma unroll
                for (int reg = 0; reg < 4; ++reg) vv[reg] = (f16)(acc[nt][reg] + bd);
                *(f16x4*)(vt + ((size_t)(b * 4 + h) * 16 + c12) * 2048 +
                          lrow0 + rt * 16 + q4 * 4) = vv;
            }
        }
    }
}

// ---------------------------------------------------------------------------
// K2: MFMA attention partials. Round-3 change: __launch_bounds__(256,8) to
// hit the <=64-VGPR tier (8 waves/SIMD; grid offers 9 blocks/CU but VGPR
// tier previously capped it at 4 waves/SIMD). Prefetch group 4->2 to cut
// ring VGPRs 16->8. exp via single v_exp_f32 (Q pre-scaled by log2e;
// hd12 Q-constant is log2e so the -6 offset stays exact in exp2 domain).
// ---------------------------------------------------------------------------
__global__ __launch_bounds__(256, 8) void k_attn_part(
    const f16* __restrict__ qh, const f16* __restrict__ kh, const f16* __restrict__ vt,
    bf16* __restrict__ part_o, float* __restrict__ part_l)
{
    const int tid = threadIdx.x;
    const int wv = tid >> 6, lane = tid & 63;
    const int quad = lane >> 4, l15 = lane & 15;
    const int bh = blockIdx.x / 36;
    int r = blockIdx.x % 36;
    int qt = 0;
    while (r >= qt + 1) { r -= qt + 1; ++qt; }
    const int ks = r;
    const int b = bh >> 2, h = bh & 3;
    const size_t base  = (size_t)b * L_ * HK_ + h * 12;
    const size_t vbase = ((size_t)bh * 16 + l15) * 2048;
    const int kbase = ks * 256;
    const int qbase = qt * 256 + wv * 64;
    const bool diag = (ks == qt);
    const int ktmax = diag ? 4 * (wv + 1) : 16;

    f16x4 Qf[4];
    #pragma unroll
    for (int s = 0; s < 4; ++s) {
        f16x4 v;
        if (quad < 3)
            v = *(const f16x4*)(qh + base + (size_t)(qbase + s * 16 + l15) * HK_ + quad * 4);
        else { v[0] = (f16)LOG2E_; v[1] = 0; v[2] = 0; v[3] = 0; }   // hd12 = log2e
        Qf[s] = v;
    }

    f32x4 O[4];
    #pragma unroll
    for (int s = 0; s < 4; ++s) O[s] = (f32x4){0.f, 0.f, 0.f, 0.f};

    for (int g = 0; g < ktmax; g += 2) {
        f16x4 Kg[2], Vg[2];
        #pragma unroll
        for (int u = 0; u < 2; ++u) {
            const int kt = g + u;
            f16x4 kf;
            if (quad < 3)
                kf = *(const f16x4*)(kh + base + (size_t)(kbase + kt * 16 + l15) * HK_ + quad * 4);
            else { kf[0] = (f16)-6.0f; kf[1] = 0; kf[2] = 0; kf[3] = 0; } // hd12 = -6
            Kg[u] = kf;
            Vg[u] = *(const f16x4*)(vt + vbase + kbase + kt * 16 + quad * 4);
        }
        #pragma unroll
        for (int u = 0; u < 2; ++u) {
            const int k0 = kbase + (g + u) * 16 + quad * 4;
            #pragma unroll
            for (int s = 0; s < 4; ++s) {
                f32x4 sc = (f32x4){0.f, 0.f, 0.f, 0.f};
                sc = __builtin_amdgcn_mfma_f32_16x16x16f16(Kg[u], Qf[s], sc, 0, 0, 0);
                float p0 = __builtin_amdgcn_exp2f(sc[0]);
                float p1 = __builtin_amdgcn_exp2f(sc[1]);
                float p2 = __builtin_amdgcn_exp2f(sc[2]);
                float p3 = __builtin_amdgcn_exp2f(sc[3]);
                if (diag) {
                    const int qg = qbase + s * 16 + l15;
                    p0 = (k0 + 0 <= qg) ? p0 : 0.f;
                    p1 = (k0 + 1 <= qg) ? p1 : 0.f;
                    p2 = (k0 + 2 <= qg) ? p2 : 0.f;
                    p3 = (k0 + 3 <= qg) ? p3 : 0.f;
                }
                const hf16x2 lo = __builtin_amdgcn_cvt_pkrtz(p0, p1);
                const hf16x2 hi = __builtin_amdgcn_cvt_pkrtz(p2, p3);
                f16x4 p;
                p[0] = (f16)lo[0]; p[1] = (f16)lo[1];
                p[2] = (f16)hi[0]; p[3] = (f16)hi[1];
                O[s] = __builtin_amdgcn_mfma_f32_16x16x16f16(p, Vg[u], O[s], 0, 0, 0);
            }
        }
    }

    const size_t pobase = (size_t)(bh * 8 + ks) * 2048;
    #pragma unroll
    for (int s = 0; s < 4; ++s) {
        const int q16 = qbase + s * 16;
        #pragma unroll
        for (int j = 0; j < 4; ++j) {
            const int qq = q16 + quad * 4 + j;
            if (l15 < 12)       part_o[(pobase + qq) * 12 + l15] = f2b(O[s][j]);
            else if (l15 == 12) part_l[pobase + qq] = O[s][j];
        }
    }
}

// ---------------------------------------------------------------------------
// K3: fused combine + out-proj (MFMA) + residual + LN2.
// Round-3 change: 32-row tiles, grid 1024 -> 4 blocks/CU. N-tiles split
// across wave pairs (6+6); LN2 row-sums combined across the pair via LDS.
// ---------------------------------------------------------------------------
__global__ __launch_bounds__(256, 4) void k_proj_ln2(
    const float* __restrict__ x, const bf16* __restrict__ part_o,
    const float* __restrict__ part_l, const bf16* __restrict__ wrepo,
    const float* __restrict__ bo, const float* __restrict__ g2,
    const float* __restrict__ lb2, bf16* __restrict__ x2b,
    bf16* __restrict__ xn2b)
{
    __shared__ bf16 ct[32 * 72];
    __shared__ float psum[4][4][4][2];   // [wave][q4][reg][{sum,ssum}]
    const int tid = threadIdx.x;
    const int wave = tid >> 6, lane = tid & 63;
    const int rowbase = blockIdx.x * 32;
    const int b = rowbase >> 11, lrow = rowbase & 2047;
    const int ns = (lrow >> 8) + 1;

    if (tid < 128) {
        const int rr = tid >> 2, h = tid & 3;
        const int q = lrow + rr;
        const bf16* op = part_o + ((size_t)(b * 4 + h) * 8 * 2048 + q) * 12;
        const float* lp = part_l + (size_t)(b * 4 + h) * 8 * 2048 + q;
        float o[12];
        #pragma unroll
        for (int i = 0; i < 12; ++i) o[i] = 0.f;
        float l = 0.f;
        for (int s = 0; s < ns; ++s) {
            l += lp[(size_t)s * 2048];
            #pragma unroll
            for (int i = 0; i < 12; ++i) o[i] += b2f(op[(size_t)s * 2048 * 12 + i]);
        }
        const float inv = 1.0f / l;
        #pragma unroll
        for (int i = 0; i < 12; ++i) ct[rr * 72 + h * 12 + i] = f2b(o[i] * inv);
        const int c0 = 48 + h * 4;
        #pragma unroll
        for (int i = 0; i < 4; ++i) ct[rr * 72 + c0 + i] = f2b(0.f);
    }
    __syncthreads();

    const int l15 = lane & 15, q4 = lane >> 4;
    const int rt = wave >> 1, g = wave & 1;
    f32x4 acc[6];
    #pragma unroll
    for (int j = 0; j < 6; ++j) acc[j] = (f32x4){0.f, 0.f, 0.f, 0.f};
    const bf16* arow = ct + (rt * 16 + l15) * 72 + q4 * 8;
    #pragma unroll
    for (int kb = 0; kb < 2; ++kb) {
        const bf16x8 a = *(const bf16x8*)(arow + kb * 32);
        const bf16* wp = wrepo + ((size_t)kb * 192 + l15) * 32 + q4 * 8
                       + (size_t)(g * 6) * 16 * 32;
        #pragma unroll
        for (int j = 0; j < 6; ++j) {
            const bf16x8 bb = *(const bf16x8*)(wp + (size_t)j * 16 * 32);
            acc[j] = __builtin_amdgcn_mfma_f32_16x16x32_bf16(a, bb, acc[j], 0, 0, 0);
        }
    }

    const int rw0 = rowbase + rt * 16 + q4 * 4;
    float sum[4] = {0.f, 0.f, 0.f, 0.f}, ssum[4] = {0.f, 0.f, 0.f, 0.f};
    #pragma unroll
    for (int j = 0; j < 6; ++j) {
        const int col = (g * 6 + j) * 16 + l15;
        const float bod = bo[col];
        #pragma unroll
        for (int reg = 0; reg < 4; ++reg) {
            const float v = acc[j][reg] + bod + x[(size_t)(rw0 + reg) * D_ + col];
            acc[j][reg] = v;
            x2b[(size_t)(rw0 + reg) * D_ + col] = f2b(v);
            sum[reg] += v; ssum[reg] += v * v;
        }
    }
    #pragma unroll
    for (int m = 1; m <= 8; m <<= 1) {
        #pragma unroll
        for (int reg = 0; reg < 4; ++reg) {
            sum[reg]  += __shfl_xor(sum[reg], m, 64);
            ssum[reg] += __shfl_xor(ssum[reg], m, 64);
        }
    }
    if (l15 == 0) {
        #pragma unroll
        for (int reg = 0; reg < 4; ++reg) {
            psum[wave][q4][reg][0] = sum[reg];
            psum[wave][q4][reg][1] = ssum[reg];
        }
    }
    __syncthreads();
    float mean[4], rs[4];
    #pragma unroll
    for (int reg = 0; reg < 4; ++reg) {
        const float st = sum[reg]  + psum[wave ^ 1][q4][reg][0];
        const float qt2 = ssum[reg] + psum[wave ^ 1][q4][reg][1];
        mean[reg] = st * (1.0f / 192.0f);
        const float var = qt2 * (1.0f / 192.0f) - mean[reg] * mean[reg];
        rs[reg] = rsqrtf(var + EPS_);
    }
    #pragma unroll
    for (int j = 0; j < 6; ++j) {
        const int col = (g * 6 + j) * 16 + l15;
        const float gg = g2[col], bb2 = lb2[col];
        #pragma unroll
        for (int reg = 0; reg < 4; ++reg)
            xn2b[(size_t)(rw0 + reg) * D_ + col] =
                f2b((acc[j][reg] - mean[reg]) * rs[reg] * gg + bb2);
    }
}

// ---------------------------------------------------------------------------
// K4: FUSED conv1+conv2. Round-3 change: 32-row tiles, grid 1024, LDS 28 KB
// (36 staged input rows + 34 h rows) -> 4 blocks/CU, 4 waves/SIMD (was 2).
// conv1: 3 M-tiles (48 rows, 34 valid h); conv2: 2 M-tiles (32 out rows).
// Stray A-reads beyond staged rows land inside the LDS allocation and feed
// only discarded h rows (MFMA D-row r depends only on A-row r).
// ---------------------------------------------------------------------------
#define INROWB 400            // LDS row stride in bytes (384 data + 16 pad)
#define NIN    36             // staged input rows (rowbase-2 .. rowbase+33)
#define NH     34             // h rows (positions lrow-1 .. lrow+32)
#define HTOFF  (NIN * INROWB) // 14400
__global__ __launch_bounds__(256, 4) void k_conv_fused(
    const bf16* __restrict__ act, const bf16* __restrict__ w1,
    const float* __restrict__ b1c, const bf16* __restrict__ w2,
    const float* __restrict__ b2c, const bf16* __restrict__ x2b,
    float* __restrict__ outf)
{
    __shared__ __align__(16) char lds[NIN * INROWB + NH * INROWB];   // 28000 B

    const int tid = threadIdx.x;
    const int wave = tid >> 6, lane = tid & 63;
    const int m16 = lane & 15, q = lane >> 4;
    const int rowbase = blockIdx.x * 32;
    const int lrow = rowbase & (L_ - 1);

    // ---- stage xn2b rows rowbase-2 .. rowbase+33 (36 rows x 384 B) ----
    {
        const bf16* src0 = act + ((long long)rowbase - 2) * D_;
        bf16x8 v[4];
        int dst[4];
        #pragma unroll
        for (int i = 0; i < 4; ++i) {
            const int g = tid + i * 256;
            if (g < 864) {
                v[i] = *(const bf16x8*)(src0 + g * 8);
                const int row = (g * 2731) >> 16;          // g / 24
                dst[i] = row * INROWB + (g - row * 24) * 16;
            }
        }
        #pragma unroll
        for (int i = 0; i < 4; ++i) {
            const int g = tid + i * 256;
            if (g < 864) *(bf16x8*)(lds + dst[i]) = v[i];
        }
    }

    const int laneA = m16 * INROWB + q * 16;  // per-lane A-fragment byte offset
    const int colw = wave * 48;
    float bd1[3], bd2[3];
    #pragma unroll
    for (int j = 0; j < 3; ++j) {
        bd1[j] = b1c[colw + j * 16 + m16];
        bd2[j] = b2c[colw + j * 16 + m16];
    }
    __syncthreads();

    // ---- conv1: 3 M-tiles (48 rows, 34 valid) x 3 N-tiles, K=576 ----
    f32x4 acc1[3][3];
    #pragma unroll
    for (int mt = 0; mt < 3; ++mt)
        #pragma unroll
        for (int j = 0; j < 3; ++j) acc1[mt][j] = (f32x4){0.f, 0.f, 0.f, 0.f};

    #define LOADB(w, kb, j) \
        (*(const bf16x8*)((w) + ((size_t)(kb) * 192 + m16) * 32 + q * 8 \
                          + (size_t)(wave * 3 + (j)) * 16 * 32))
    {
        bf16x8 bB[2][3];
        #pragma unroll
        for (int j = 0; j < 3; ++j) bB[0][j] = LOADB(w1, 0, j);
        #pragma unroll
        for (int kb = 0; kb < 18; ++kb) {
            if (kb + 1 < 18) {
                #pragma unroll
                for (int j = 0; j < 3; ++j) bB[(kb + 1) & 1][j] = LOADB(w1, kb + 1, j);
            }
            const int t = kb / 6, c6 = kb % 6;
            bf16x8 a[3];
            #pragma unroll
            for (int mt = 0; mt < 3; ++mt)
                a[mt] = *(const bf16x8*)(lds + laneA + (mt * 16 + t) * INROWB + c6 * 64);
            #pragma unroll
            for (int j = 0; j < 3; ++j)
                #pragma unroll
                for (int mt = 0; mt < 3; ++mt)
                    acc1[mt][j] = __builtin_amdgcn_mfma_f32_16x16x32_bf16(
                        a[mt], bB[kb & 1][j], acc1[mt][j], 0, 0, 0);
        }
    }

    // ---- h-tile (relu, edge-zero) -> LDS rows 0..33 ----
    #pragma unroll
    for (int mt = 0; mt < 3; ++mt)
        #pragma unroll
        for (int j = 0; j < 3; ++j)
            #pragma unroll
            for (int reg = 0; reg < 4; ++reg) {
                const int hr = mt * 16 + q * 4 + reg;
                if (hr < NH) {
                    const int hm = lrow + hr - 1;
                    float v = fmaxf(acc1[mt][j][reg] + bd1[j], 0.f);
                    if (hm == 0 || hm == L_ - 1) v = 0.f;
                    *(bf16*)(lds + HTOFF + hr * INROWB + (colw + j * 16 + m16) * 2) = f2b(v);
                }
            }

    // ---- preload residual x2b (latency hidden under barrier + conv2) ----
    float xr[3][2][4];
    #pragma unroll
    for (int j = 0; j < 3; ++j)
        #pragma unroll
        for (int mt = 0; mt < 2; ++mt)
            #pragma unroll
            for (int reg = 0; reg < 4; ++reg)
                xr[j][mt][reg] = b2f(x2b[(size_t)(rowbase + mt * 16 + q * 4 + reg) * D_
                                         + colw + j * 16 + m16]);
    __syncthreads();

    // ---- conv2: 2 M-tiles x 3 N-tiles, A from h-tile ----
    f32x4 acc2[2][3];
    #pragma unroll
    for (int mt = 0; mt < 2; ++mt)
        #pragma unroll
        for (int j = 0; j < 3; ++j) acc2[mt][j] = (f32x4){0.f, 0.f, 0.f, 0.f};
    {
        bf16x8 bB[2][3];
        #pragma unroll
        for (int j = 0; j < 3; ++j) bB[0][j] = LOADB(w2, 0, j);
        #pragma unroll
        for (int kb = 0; kb < 18; ++kb) {
            if (kb + 1 < 18) {
                #pragma unroll
                for (int j = 0; j < 3; ++j) bB[(kb + 1) & 1][j] = LOADB(w2, kb + 1, j);
            }
            const int t = kb / 6, c6 = kb % 6;
            bf16x8 a[2];
            #pragma unroll
            for (int mt = 0; mt < 2; ++mt)
                a[mt] = *(const bf16x8*)(lds + HTOFF + laneA + (mt * 16 + t) * INROWB + c6 * 64);
            #pragma unroll
            for (int j = 0; j < 3; ++j)
                #pragma unroll
                for (int mt = 0; mt < 2; ++mt)
                    acc2[mt][j] = __builtin_amdgcn_mfma_f32_16x16x32_bf16(
                        a[mt], bB[kb & 1][j], acc2[mt][j], 0, 0, 0);
        }
    }
    #undef LOADB

    // ---- epilogue: residual + store f32 ----
    #pragma unroll
    for (int j = 0; j < 3; ++j)
        #pragma unroll
        for (int mt = 0; mt < 2; ++mt)
            #pragma unroll
            for (int reg = 0; reg < 4; ++reg) {
                const int r = rowbase + mt * 16 + q * 4 + reg;
                const int m = r & (L_ - 1);
                float v = xr[j][mt][reg];
                if (m != 0 && m != L_ - 1) v += acc2[mt][j][reg] + bd2[j];
                outf[(size_t)r * D_ + colw + j * 16 + m16] = v;
            }
}

// ---------------------------------------------------------------------------
extern "C" void kernel_launch(void* const* d_in, const int* in_sizes, int n_in,
                              void* d_out, int out_size, void* d_ws, size_t ws_size,
                              hipStream_t stream)
{
    const float* x    = (const float*)d_in[0];
    const float* ln1g = (const float*)d_in[1];
    const float* ln1b = (const float*)d_in[2];
    const float* wq   = (const float*)d_in[3];
    const float* bq   = (const float*)d_in[4];
    const float* wk   = (const float*)d_in[5];
    const float* bk   = (const float*)d_in[6];
    const float* wv   = (const float*)d_in[7];
    const float* bv   = (const float*)d_in[8];
    const float* wo   = (const float*)d_in[9];
    const float* bo   = (const float*)d_in[10];
    const float* ln2g = (const float*)d_in[11];
    const float* ln2b = (const float*)d_in[12];
    const float* c1w  = (const float*)d_in[13];
    const float* c1b  = (const float*)d_in[14];
    const float* c2w  = (const float*)d_in[15];
    const float* c2b  = (const float*)d_in[16];

    const size_t ROWS = (size_t)16 * L_;            // 32768
    char* ws = (char*)d_ws;
    size_t off = 4096;                               // guard (conv halo row -2)
    bf16* xn2b = (bf16*)(ws + off); off += ROWS * D_ * 2;    // 12.6 MB
    off += 4096;                                     // guard (conv halo row +33)
    bf16* hpb  = (bf16*)(ws + off); off += ROWS * D_ * 2;    // (unused, keeps guard)
    off += 4096;                                     // guard
    bf16* x2b  = (bf16*)(ws + off); off += ROWS * D_ * 2;    // 12.6 MB
    f16* qb    = (f16*)(ws + off);   off += ROWS * HK_ * 2;  // 3.15 MB
    f16* kb    = (f16*)(ws + off);   off += ROWS * HK_ * 2;
    f16* vt    = (f16*)(ws + off);   off += (size_t)64 * 16 * 2048 * 2;   // 4.19 MB
    bf16* part_o = (bf16*)(ws + off); off += (size_t)64 * 8 * 2048 * 12 * 2; // 25.2 MB
    float* part_l = (float*)(ws + off); off += (size_t)64 * 8 * 2048 * 4;    //  4.2 MB
    bf16* wrep1 = (bf16*)(ws + off); off += 576 * 192 * 2;   // 221 KB
    bf16* wrep2 = (bf16*)(ws + off); off += 576 * 192 * 2;
    bf16* wrepq = (bf16*)(ws + off); off += 6 * 144 * 32 * 2;
    float* bias144 = (float*)(ws + off); off += 144 * 4;
    bf16* wrepo = (bf16*)(ws + off); off += 2 * 192 * 32 * 2; // total ~83 MB

    (void)hpb;
    k_prep_all   <<<1021, 256, 0, stream>>>(c1w, c2w, wq, wk, wv, bq, bk, bv, wo,
                                            wrep1, wrep2, wrepq, bias144, wrepo);
    k_ln_qkv     <<<1024, 256, 0, stream>>>(x, ln1g, ln1b, wrepq, bias144, qb, kb, vt);
    k_attn_part  <<<64 * 36, 256, 0, stream>>>(qb, kb, vt, part_o, part_l);
    k_proj_ln2   <<<1024, 256, 0, stream>>>(x, part_o, part_l, wrepo, bo, ln2g, ln2b,
                                            x2b, xn2b);
    k_conv_fused <<<1024, 256, 0, stream>>>(xn2b, wrep1, c1b, wrep2, c2b, x2b,
                                            (float*)d_out);
}